// Round 9
// baseline (268.921 us; speedup 1.0000x reference)
//
#include <hip/hip_runtime.h>
#include <math.h>

// Problem constants: B=4, H=W=64, M=8, K=64
#define HW  4096
#define KK  64
#define WPB 4
#define BLK (WPB*64)

__device__ __forceinline__ float softplusf(float x) {
    return fmaxf(x, 0.0f) + log1pf(expf(-fabsf(x)));
}

// 64-lane min via fused v_min_u32_dpp chain (verified absmax 0.0, r6).
__device__ __forceinline__ unsigned wave_min_u32(unsigned x) {
    asm("s_nop 1\n\t"
        "v_min_u32_dpp %0, %0, %0 row_shr:1  row_mask:0xf bank_mask:0xf\n\t"
        "s_nop 1\n\t"
        "v_min_u32_dpp %0, %0, %0 row_shr:2  row_mask:0xf bank_mask:0xf\n\t"
        "s_nop 1\n\t"
        "v_min_u32_dpp %0, %0, %0 row_shr:4  row_mask:0xf bank_mask:0xf\n\t"
        "s_nop 1\n\t"
        "v_min_u32_dpp %0, %0, %0 row_shr:8  row_mask:0xf bank_mask:0xf\n\t"
        "s_nop 1\n\t"
        "v_min_u32_dpp %0, %0, %0 row_bcast:15 row_mask:0xf bank_mask:0xf\n\t"
        "s_nop 1\n\t"
        "v_min_u32_dpp %0, %0, %0 row_bcast:31 row_mask:0xf bank_mask:0xf\n\t"
        "s_nop 1"
        : "+v"(x));
    return (unsigned)__builtin_amdgcn_readlane((int)x, 63);
}

// VAR 0: r6 control (fused DPP, branchy unroll-64, cl->INF exclusion)
// VAR 1: V0 with cross-lane reduce replaced by 1-op opaque fake
// VAR 2: no greedy loop (prologue/epilogue floor)
// VAR 3: V0 branchless (all 64 steps, scalar gate, no branches)
template<int VAR, int REPS>
__global__ __launch_bounds__(BLK) void assign_var(
    const float*  __restrict__ ps,
    const float2* __restrict__ po,
    const int*    __restrict__ tgt,
    float* __restrict__ pobj, float* __restrict__ ploc, int* __restrict__ pnp)
{
    const int lane = threadIdx.x & 63;
    const int wib  = threadIdx.x >> 6;
    const int wid  = blockIdx.x * WPB + wib;

    const int b = wid >> 12;
    const int n = wid & (HW - 1);
    const int h = n >> 6, w = n & 63;

    const int base = wid * KK + lane;
    const float  s  = ps[base];
    const float2 pv = po[base];
    const float po0_ = pv.x, po1_ = pv.y;

    const int ti = lane >> 3, tj = lane & 7;
    const int tv = tgt[((b * 512) + h * 8 + ti) * 512 + (w * 8 + tj)] > 0;
    const unsigned long long mask = __ballot(tv);
    const int npos = __popcll(mask);

    const float sig = 1.0f / (1.0f + expf(-s));
    const float cl0 = sqrtf(sqrtf(1.0f - sig));
    const float FINF = __builtin_huge_valf();

    float focal0 = 0.0f, locl0 = 0.0f;   // rep-0 results (stored)

    for (int r = 0; r < REPS; ++r) {
        // opaque pass-through: defeats cross-rep CSE (bits unchanged)
        float po0 = po0_, po1 = po1_, cl = cl0;
        asm volatile("" : "+v"(po0), "+v"(po1), "+v"(cl));

        float locl = 0.0f;

        if (VAR == 0 || VAR == 1) {
            #pragma unroll 64
            for (int t = 0; t < 64; ++t) {
                if (mask & (1ull << (unsigned long long)t)) {
                    const float by = (float)(t >> 3) * 0.125f - 0.4375f;
                    const float bx = (float)(t & 7)  * 0.125f - 0.4375f;
                    const float loc = fabsf(po0 - by) + fabsf(po1 - bx);
                    const float c   = loc * cl;
                    const unsigned key =
                        (__float_as_uint(c) & ~63u) | (unsigned)lane;
                    unsigned mn;
                    if (VAR == 0) mn = wave_min_u32(key);
                    else          mn = key & (unsigned)mask;  // opaque fake, 1 op
                    const bool win = (key == mn);
                    cl   = win ? FINF : cl;
                    locl = win ? loc  : locl;
                }
            }
        } else if (VAR == 3) {
            #pragma unroll 64
            for (int t = 0; t < 64; ++t) {
                const unsigned live = (unsigned)((mask >> t) & 1ull); // scalar
                const float by = (float)(t >> 3) * 0.125f - 0.4375f;
                const float bx = (float)(t & 7)  * 0.125f - 0.4375f;
                const float loc = fabsf(po0 - by) + fabsf(po1 - bx);
                const float c   = loc * cl;
                const unsigned key =
                    (__float_as_uint(c) & ~63u) | (unsigned)lane;
                const unsigned kc = key | (live - 1u);  // dead -> 0xFFFFFFFF
                const unsigned mn = wave_min_u32(kc);
                const bool win = ((unsigned)lane == (mn & 63u)) && (live != 0u);
                cl   = win ? FINF : cl;
                locl = win ? loc  : locl;
            }
        }
        // VAR == 2: no loop

        bool assigned;
        if (VAR == 2) assigned = (tv != 0);
        else          assigned = (cl > 1e30f);
        const float ce  = assigned ? softplusf(-s) : softplusf(s);
        const float p_t = assigned ? sig : (1.0f - sig);
        const float om  = 1.0f - p_t;
        float focal = ce * om * om * (assigned ? 0.6f : 0.4f);
        if (!assigned) locl = 0.0f;

        // keep every rep's results live (defeats DCE of reps > 0)
        asm volatile("" :: "v"(focal), "v"(locl));
        if (r == 0) { focal0 = focal; locl0 = locl; }
    }

    float focal = focal0, locs = locl0;
    #pragma unroll
    for (int o = 32; o; o >>= 1) {
        focal += __shfl_xor(focal, o, 64);
        locs  += __shfl_xor(locs,  o, 64);
    }

    __shared__ float sobj[WPB], sloc[WPB];
    __shared__ int   snp[WPB];
    if (lane == 0) { sobj[wib] = focal; sloc[wib] = locs; snp[wib] = npos; }
    __syncthreads();
    if (threadIdx.x == 0) {
        float o = 0.0f, l = 0.0f; int np = 0;
        #pragma unroll
        for (int q = 0; q < WPB; ++q) { o += sobj[q]; l += sloc[q]; np += snp[q]; }
        pobj[blockIdx.x] = o;
        ploc[blockIdx.x] = l;
        pnp [blockIdx.x] = np;
    }
}

__global__ __launch_bounds__(256) void finalize_kernel(
    const float* __restrict__ pobj,
    const float* __restrict__ ploc,
    const int*   __restrict__ pnp,
    int nb, float* __restrict__ out)
{
    __shared__ double so[256], sl[256];
    __shared__ long long sn[256];
    double o = 0.0, l = 0.0;
    long long np = 0;
    for (int i = threadIdx.x; i < nb; i += 256) {
        o  += (double)pobj[i];
        l  += (double)ploc[i];
        np += (long long)pnp[i];
    }
    so[threadIdx.x] = o; sl[threadIdx.x] = l; sn[threadIdx.x] = np;
    __syncthreads();
    for (int st = 128; st; st >>= 1) {
        if (threadIdx.x < st) {
            so[threadIdx.x] += so[threadIdx.x + st];
            sl[threadIdx.x] += sl[threadIdx.x + st];
            sn[threadIdx.x] += sn[threadIdx.x + st];
        }
        __syncthreads();
    }
    if (threadIdx.x == 0) {
        long long npos = sn[0] > 1 ? sn[0] : 1;
        out[0] = (float)((so[0] + 10.0 * sl[0]) / (double)npos);
    }
}

extern "C" void kernel_launch(void* const* d_in, const int* in_sizes, int n_in,
                              void* d_out, int out_size, void* d_ws, size_t ws_size,
                              hipStream_t stream) {
    const float*  ps  = (const float*)d_in[0];
    const float2* po  = (const float2*)d_in[1];
    const int*    tgt = (const int*)d_in[2];

    const int total_blocks = in_sizes[0] / KK;          // 16384
    const int nwg = total_blocks / WPB;                 // 4096

    float* W = (float*)d_ws;
    // real partials (V0)
    float* pobj = W;            float* ploc = W + 4096;
    int*   pnp  = (int*)(W + 8192);
    // dead scratch per variant
    float* s1 = W + 16384;  float* s2 = W + 32768;  float* s3 = W + 49152;

    // control (r6 structure) -> real partials
    assign_var<0, 4><<<nwg, BLK, 0, stream>>>(ps, po, tgt, pobj, ploc, pnp);
    // ablations -> scratch
    assign_var<1, 8><<<nwg, BLK, 0, stream>>>(ps, po, tgt,
        s1, s1 + 4096, (int*)(s1 + 8192));
    assign_var<2,16><<<nwg, BLK, 0, stream>>>(ps, po, tgt,
        s2, s2 + 4096, (int*)(s2 + 8192));
    assign_var<3, 4><<<nwg, BLK, 0, stream>>>(ps, po, tgt,
        s3, s3 + 4096, (int*)(s3 + 8192));

    finalize_kernel<<<1, 256, 0, stream>>>(pobj, ploc, pnp, nwg, (float*)d_out);
}

// Round 10
// 34.382 us; speedup vs baseline: 7.8217x; 7.8217x over previous
//
#include <hip/hip_runtime.h>
#include <math.h>

// Problem constants: B=4, H=W=64, M=8, K=64
#define HW  4096
#define KK  64
#define BLK 256          // 4 waves per workgroup
#define BPW 4            // blocks per wave (one per 16-lane group)

__device__ __forceinline__ unsigned umin32(unsigned a, unsigned b) { return a < b ? a : b; }

__device__ __forceinline__ float softplusf(float x) {
    return fmaxf(x, 0.0f) + log1pf(expf(-fabsf(x)));
}

// 16-lane-group min via 4 fused v_min_u32_dpp rotation-butterfly levels.
// row_ror:N rotates within a 16-lane row, so combining rotations 1,2,4,8
// leaves EVERY lane of the row holding the row min - no cross-half-wave
// bcast, no readlane. s_nop 1 supplies the 2 DPP wait states (r5 lesson:
// raw DPP without wait states reads stale data).
__device__ __forceinline__ unsigned group_min_u32(unsigned x) {
    asm("s_nop 1\n\t"
        "v_min_u32_dpp %0, %0, %0 row_ror:1 row_mask:0xf bank_mask:0xf\n\t"
        "s_nop 1\n\t"
        "v_min_u32_dpp %0, %0, %0 row_ror:2 row_mask:0xf bank_mask:0xf\n\t"
        "s_nop 1\n\t"
        "v_min_u32_dpp %0, %0, %0 row_ror:4 row_mask:0xf bank_mask:0xf\n\t"
        "s_nop 1\n\t"
        "v_min_u32_dpp %0, %0, %0 row_ror:8 row_mask:0xf bank_mask:0xf\n\t"
        "s_nop 1"
        : "+v"(x));
    return x;
}

// Wave = 4 groups x 16 lanes; group g owns block bid = wv*4+g.
// Lane q owns prediction slots q*4+u (contiguous, float4 loads - r6-verified
// mapping) and target cells c = q + 16v (strided, so the 64-bit group mask
// assembles from 4 ballots with shifts only; cell c = raster index i*8+j).
__global__ __launch_bounds__(BLK) void assign_loss_kernel(
    const float4* __restrict__ ps4,   // pred_scores  as float4
    const float4* __restrict__ po4,   // pred_offsets as float4
    const int*    __restrict__ tgt,   // [B,512,512]
    float* __restrict__ pobj, float* __restrict__ ploc, int* __restrict__ pnp)
{
    const int lane = threadIdx.x & 63;
    const int wib  = threadIdx.x >> 6;
    const int wv   = blockIdx.x * 4 + wib;     // wave id (4096 total)
    const int g    = lane >> 4;
    const int q    = lane & 15;
    const int bid  = wv * BPW + g;             // 0..16383
    const int b    = bid >> 12;
    const int n    = bid & (HW - 1);
    const int h    = n >> 6, w = n & 63;

    // predictions (coalesced): slots q*4..q*4+3
    const float4 sc = ps4[bid * 16 + q];
    const float4 pa = po4[bid * 32 + q * 2];
    const float4 pb = po4[bid * 32 + q * 2 + 1];
    float p0[4] = {pa.x, pa.z, pb.x, pb.z};
    float p1[4] = {pa.y, pa.w, pb.y, pb.w};
    float s [4] = {sc.x, sc.y, sc.z, sc.w};

    // target cells c = q+16v: tile row (q>>3)+2v, col q&7
    const int rb = (b * 512 + h * 8 + (q >> 3)) * 512 + w * 8 + (q & 7);
    int bb[4];
    #pragma unroll
    for (int v = 0; v < 4; ++v) bb[v] = tgt[rb + v * 1024] > 0;
    int cnt = bb[0] + bb[1] + bb[2] + bb[3];   // each cell counted once

    const unsigned long long B0 = __ballot(bb[0]);
    const unsigned long long B1 = __ballot(bb[1]);
    const unsigned long long B2 = __ballot(bb[2]);
    const unsigned long long B3 = __ballot(bb[3]);
    const int sh = g * 16;
    const unsigned w0 = (unsigned)(B0 >> sh) & 0xFFFFu;
    const unsigned w1 = (unsigned)(B1 >> sh) & 0xFFFFu;
    const unsigned w2 = (unsigned)(B2 >> sh) & 0xFFFFu;
    const unsigned w3 = (unsigned)(B3 >> sh) & 0xFFFFu;
    unsigned mlo = w0 | (w1 << 16);            // group mask bits 0..31
    unsigned mhi = w2 | (w3 << 16);            // bits 32..63 (raster order)

    float sig[4], cl[4], locl[4];
    unsigned dead[4] = {0u, 0u, 0u, 0u};
    #pragma unroll
    for (int u = 0; u < 4; ++u) {
        sig[u]  = 1.0f / (1.0f + expf(-s[u]));
        cl[u]   = sqrtf(sqrtf(1.0f - sig[u]));  // order-equiv ^0.25 factor
        locl[u] = 0.0f;
    }

    // greedy: one cell per iteration per group; loop until all 4 groups done
    while (__any((mlo | mhi) != 0u)) {
        const unsigned gd = ((mlo | mhi) == 0u) ? ~0u : 0u;  // group finished
        const int t = (mlo != 0u) ? (__ffs(mlo) - 1) : (31 + __ffs(mhi));
        const unsigned nhi = (mlo == 0u) ? (mhi & (mhi - 1u)) : mhi;
        mlo &= (mlo - 1u);
        mhi = nhi;

        const float by = (float)(t >> 3) * 0.125f - 0.4375f;  // exact
        const float bx = (float)(t & 7)  * 0.125f - 0.4375f;  // exact

        float l[4]; unsigned kc[4];
        #pragma unroll
        for (int u = 0; u < 4; ++u) {
            l[u]  = fabsf(p0[u] - by) + fabsf(p1[u] - bx);
            // clean key: cost bits (>=0, finite) | slot id; unique per slot,
            // u32-min == cost argmin with first-index tie-break (r2-r7 verified)
            kc[u] = (__float_as_uint(l[u] * cl[u]) & ~63u) | (unsigned)(q * 4 + u);
        }
        unsigned x = umin32(umin32(kc[0] | dead[0], kc[1] | dead[1]),
                            umin32(kc[2] | dead[2], kc[3] | dead[3])) | gd;
        x = group_min_u32(x);   // all 16 lanes get group min
        // winner: clean key == group min. Dead slots / finished groups can't
        // match (their contribution was 0xFFFFFFFF; clean keys are finite).
        #pragma unroll
        for (int u = 0; u < 4; ++u) {
            const bool win = (kc[u] == x);
            dead[u] = win ? ~0u : dead[u];
            locl[u] = win ? l[u] : locl[u];   // each slot wins <= once
        }
    }

    // losses
    float focal = 0.0f, locs = 0.0f;
    #pragma unroll
    for (int u = 0; u < 4; ++u) {
        const bool asg = (dead[u] != 0u);
        const float ce  = asg ? softplusf(-s[u]) : softplusf(s[u]);
        const float p_t = asg ? sig[u] : (1.0f - sig[u]);
        const float om  = 1.0f - p_t;
        focal += ce * om * om * (asg ? 0.6f : 0.4f);
        locs  += locl[u];
    }

    float fc = focal, lc = locs; int cc = cnt;
    #pragma unroll
    for (int o = 32; o; o >>= 1) {
        fc += __shfl_xor(fc, o, 64);
        lc += __shfl_xor(lc, o, 64);
        cc += __shfl_xor(cc, o, 64);
    }

    __shared__ float sobj[4], sloc[4];
    __shared__ int   snp[4];
    if (lane == 0) { sobj[wib] = fc; sloc[wib] = lc; snp[wib] = cc; }
    __syncthreads();
    if (threadIdx.x == 0) {
        float o = 0.0f, l = 0.0f; int np = 0;
        #pragma unroll
        for (int u = 0; u < 4; ++u) { o += sobj[u]; l += sloc[u]; np += snp[u]; }
        pobj[blockIdx.x] = o;
        ploc[blockIdx.x] = l;
        pnp [blockIdx.x] = np;
    }
}

__global__ __launch_bounds__(256) void finalize_kernel(
    const float* __restrict__ pobj,
    const float* __restrict__ ploc,
    const int*   __restrict__ pnp,
    int nb, float* __restrict__ out)
{
    __shared__ double so[256], sl[256];
    __shared__ long long sn[256];
    double o = 0.0, l = 0.0;
    long long np = 0;
    for (int i = threadIdx.x; i < nb; i += 256) {
        o  += (double)pobj[i];
        l  += (double)ploc[i];
        np += (long long)pnp[i];
    }
    so[threadIdx.x] = o; sl[threadIdx.x] = l; sn[threadIdx.x] = np;
    __syncthreads();
    for (int st = 128; st; st >>= 1) {
        if (threadIdx.x < st) {
            so[threadIdx.x] += so[threadIdx.x + st];
            sl[threadIdx.x] += sl[threadIdx.x + st];
            sn[threadIdx.x] += sn[threadIdx.x + st];
        }
        __syncthreads();
    }
    if (threadIdx.x == 0) {
        long long npos = sn[0] > 1 ? sn[0] : 1;
        out[0] = (float)((so[0] + 10.0 * sl[0]) / (double)npos);
    }
}

extern "C" void kernel_launch(void* const* d_in, const int* in_sizes, int n_in,
                              void* d_out, int out_size, void* d_ws, size_t ws_size,
                              hipStream_t stream) {
    const float4* ps4 = (const float4*)d_in[0];
    const float4* po4 = (const float4*)d_in[1];
    const int*    tgt = (const int*)d_in[2];

    const int total_blocks = in_sizes[0] / KK;     // 16384
    const int nwg = total_blocks / 16;             // 1024 (16 blocks per wg)

    float* pobj = (float*)d_ws;
    float* ploc = pobj + nwg;
    int*   pnp  = (int*)(ploc + nwg);

    assign_loss_kernel<<<nwg, BLK, 0, stream>>>(ps4, po4, tgt, pobj, ploc, pnp);
    finalize_kernel<<<1, 256, 0, stream>>>(pobj, ploc, pnp, nwg, (float*)d_out);
}